// Round 5
// baseline (270.569 us; speedup 1.0000x reference)
//
#include <hip/hip_runtime.h>
#include <cstdint>

typedef __attribute__((ext_vector_type(8))) short short8;
typedef __attribute__((ext_vector_type(4))) float floatx4;

__device__ __forceinline__ unsigned short f2bf(float f) {
  uint32_t u = __builtin_bit_cast(uint32_t, f);
  u += 0x7fffu + ((u >> 16) & 1u);   // RNE
  return (unsigned short)(u >> 16);
}

// ---------------- kernel 1: W transpose + convert (fp32 -> bf16) ----------------
// Wt_all[576][768]; row n = which*192+nn holds W_which[:, nn]
__global__ void prep_w_kernel(const float* __restrict__ Wq,
                              const float* __restrict__ Wk,
                              const float* __restrict__ Wv,
                              unsigned short* __restrict__ Wt) {
  int idx = blockIdx.x * 256 + threadIdx.x;
  if (idx >= 576 * 768) return;
  int n = idx / 768;
  int k = idx - n * 768;
  int which = n / 192;
  int nn = n - which * 192;
  const float* W = (which == 0) ? Wq : (which == 1) ? Wk : Wv;
  Wt[idx] = f2bf(W[k * 192 + nn]);
}

// ---------------- kernel 2: QKV projection + RoPE ----------------
// grid (256 m-tiles, 3 which). Tile: 128 rows x 192 cols, BK=32.
__global__ __launch_bounds__(256) void proj_kernel(
    const float* __restrict__ x, const unsigned short* __restrict__ Wt_all,
    unsigned short* __restrict__ q_ws, unsigned short* __restrict__ k_ws,
    unsigned short* __restrict__ v_ws) {
  // rows padded to 40 shorts (80 B = 20 dwords -> b128 reads are 2-way max, free)
  __shared__ __align__(16) unsigned short A_lds[128 * 40];
  __shared__ __align__(16) unsigned short B_lds[192 * 40];
  const int tid = threadIdx.x;
  const int w = tid >> 6, l = tid & 63, quad = l >> 4, ln = l & 15;
  const int m0 = blockIdx.x * 128;
  const int which = blockIdx.y;
  const unsigned short* Wt = Wt_all + which * 192 * 768;

  floatx4 acc[2][12];
#pragma unroll
  for (int mt = 0; mt < 2; ++mt)
#pragma unroll
    for (int nt = 0; nt < 12; ++nt) acc[mt][nt] = floatx4{0.f, 0.f, 0.f, 0.f};

  for (int kb = 0; kb < 24; ++kb) {
    const int k0 = kb * 32;
    // stage A: x[m0..m0+127][k0..k0+31] fp32 -> bf16, 1024 float4 chunks
#pragma unroll
    for (int it = 0; it < 4; ++it) {
      int qi = it * 256 + tid;
      int row = qi >> 3, c4 = qi & 7;
      float4 f = *(const float4*)(x + (size_t)(m0 + row) * 768 + k0 + c4 * 4);
      ushort4 p;
      p.x = f2bf(f.x); p.y = f2bf(f.y); p.z = f2bf(f.z); p.w = f2bf(f.w);
      *(ushort4*)&A_lds[row * 40 + c4 * 4] = p;
    }
    // stage B: Wt[n][k0..k0+31], 768 uint4 chunks
#pragma unroll
    for (int it = 0; it < 3; ++it) {
      int idx = it * 256 + tid;
      int n = idx >> 2, c = idx & 3;
      uint4 v = *(const uint4*)(Wt + n * 768 + k0 + c * 8);
      *(uint4*)&B_lds[n * 40 + c * 8] = v;
    }
    __syncthreads();
    short8 a0 = *(const short8*)&A_lds[(w * 32 + ln) * 40 + quad * 8];
    short8 a1 = *(const short8*)&A_lds[(w * 32 + 16 + ln) * 40 + quad * 8];
#pragma unroll
    for (int nt = 0; nt < 12; ++nt) {
      short8 bfr = *(const short8*)&B_lds[(nt * 16 + ln) * 40 + quad * 8];
      acc[0][nt] = __builtin_amdgcn_mfma_f32_16x16x32_bf16(a0, bfr, acc[0][nt], 0, 0, 0);
      acc[1][nt] = __builtin_amdgcn_mfma_f32_16x16x32_bf16(a1, bfr, acc[1][nt], 0, 0, 0);
    }
    __syncthreads();
  }

  // epilogue: RoPE on cols 0..31 for Q/K, store. V stored transposed [b][dim][t].
#pragma unroll
  for (int mt = 0; mt < 2; ++mt) {
#pragma unroll
    for (int r = 0; r < 4; ++r) {
      int row_g = m0 + w * 32 + mt * 16 + quad * 4 + r;
      int t_pos = row_g & 511;
      float vals[12];
#pragma unroll
      for (int nt = 0; nt < 12; ++nt) vals[nt] = acc[mt][nt][r];
      if (which < 2) {
#pragma unroll
        for (int nt = 0; nt < 2; ++nt) {
          int col = nt * 16 + ln;
          float v = vals[nt];
          float pv = __shfl_xor(v, 1);
          int i = col >> 1;
          float inv_freq = exp2f(-(float)i * (13.287712379549449f / 16.0f));
          float ang = (float)t_pos * inv_freq;
          float sv, cv;
          sincosf(ang, &sv, &cv);
          vals[nt] = (col & 1) ? (v * cv + pv * sv) : (v * cv - pv * sv);
        }
      }
      if (which == 2) {
        int bb = row_g >> 9, t = row_g & 511;
#pragma unroll
        for (int nt = 0; nt < 12; ++nt)
          v_ws[(bb * 192 + nt * 16 + ln) * 512 + t] = f2bf(vals[nt]);
      } else {
        unsigned short* dst = (which == 0) ? q_ws : k_ws;
#pragma unroll
        for (int nt = 0; nt < 12; ++nt)
          dst[row_g * 192 + nt * 16 + ln] = f2bf(vals[nt]);
      }
    }
  }
}

// ---------------- kernel 3: causal flash attention (MFMA) ----------------
// grid (8 q-tiles, 64 batches), block 256 (4 waves). Wave w owns Q rows w*16..w*16+15.
__global__ __launch_bounds__(256) void attn_kernel(
    const unsigned short* __restrict__ q_ws, const unsigned short* __restrict__ k_ws,
    const unsigned short* __restrict__ v_ws, float* __restrict__ out) {
  __shared__ __align__(16) unsigned short K_lds[64 * 200];
  __shared__ __align__(16) unsigned short V_lds[192 * 72];   // V^T: [dim][key]
  __shared__ __align__(16) unsigned short P_lds[4][16 * 72]; // per-wave P
  const int tid = threadIdx.x;
  const int w = tid >> 6, l = tid & 63, quad = l >> 4, ln = l & 15;
  const int qt = blockIdx.x, b = blockIdx.y;
  const int q0 = qt * 64;

  // preload Q A-fragments (rows w*16+ln, dims kk*32+quad*8..+7)
  short8 qf[6];
  {
    const unsigned short* qp =
        q_ws + (size_t)(b * 512 + q0 + w * 16 + ln) * 192 + quad * 8;
#pragma unroll
    for (int kk = 0; kk < 6; ++kk) qf[kk] = *(const short8*)(qp + kk * 32);
  }

  float m_i[4], l_i[4];
  floatx4 o[12];
#pragma unroll
  for (int r = 0; r < 4; ++r) { m_i[r] = -1e30f; l_i[r] = 0.f; }
#pragma unroll
  for (int nt = 0; nt < 12; ++nt) o[nt] = floatx4{0.f, 0.f, 0.f, 0.f};
  const float sm_scale = 0.07216878364870323f;  // 192^-0.5

  for (int kt = 0; kt <= qt; ++kt) {
    const int k0 = kt * 64;
    __syncthreads();  // previous iteration's PV reads done before overwrite
    // stage K tile [64][192]
#pragma unroll
    for (int it = 0; it < 6; ++it) {
      int idx = it * 256 + tid;
      int row = idx / 24, c = idx - row * 24;
      uint4 v = *(const uint4*)(k_ws + (size_t)(b * 512 + k0 + row) * 192 + c * 8);
      *(uint4*)&K_lds[row * 200 + c * 8] = v;
    }
    // stage V^T tile [192][64]
#pragma unroll
    for (int it = 0; it < 6; ++it) {
      int idx = it * 256 + tid;
      int row = idx >> 3, c = idx & 7;
      uint4 v = *(const uint4*)(v_ws + (size_t)(b * 192 + row) * 512 + k0 + c * 8);
      *(uint4*)&V_lds[row * 72 + c * 8] = v;
    }
    __syncthreads();

    // S = Q K^T (scaled)
    float s[4][4];
#pragma unroll
    for (int nt = 0; nt < 4; ++nt) {
      floatx4 sa = floatx4{0.f, 0.f, 0.f, 0.f};
#pragma unroll
      for (int kk = 0; kk < 6; ++kk) {
        short8 kf = *(const short8*)&K_lds[(nt * 16 + ln) * 200 + kk * 32 + quad * 8];
        sa = __builtin_amdgcn_mfma_f32_16x16x32_bf16(qf[kk], kf, sa, 0, 0, 0);
      }
#pragma unroll
      for (int r = 0; r < 4; ++r) s[nt][r] = sa[r] * sm_scale;
    }
    if (kt == qt) {  // diagonal tile: mask key > row (local indices, k0==q0)
#pragma unroll
      for (int nt = 0; nt < 4; ++nt)
#pragma unroll
        for (int r = 0; r < 4; ++r)
          if (nt * 16 + ln > w * 16 + quad * 4 + r) s[nt][r] = -1e30f;
    }
    // online softmax (row = quad*4+r; cols live in the quad's 16 lanes x 4 regs)
    float alpha[4];
#pragma unroll
    for (int r = 0; r < 4; ++r) {
      float mx = fmaxf(fmaxf(s[0][r], s[1][r]), fmaxf(s[2][r], s[3][r]));
      mx = fmaxf(mx, __shfl_xor(mx, 1));
      mx = fmaxf(mx, __shfl_xor(mx, 2));
      mx = fmaxf(mx, __shfl_xor(mx, 4));
      mx = fmaxf(mx, __shfl_xor(mx, 8));
      float mnew = fmaxf(m_i[r], mx);
      alpha[r] = __expf(m_i[r] - mnew);
      float sum = 0.f;
#pragma unroll
      for (int nt = 0; nt < 4; ++nt) {
        s[nt][r] = __expf(s[nt][r] - mnew);
        sum += s[nt][r];
      }
      sum += __shfl_xor(sum, 1);
      sum += __shfl_xor(sum, 2);
      sum += __shfl_xor(sum, 4);
      sum += __shfl_xor(sum, 8);
      l_i[r] = l_i[r] * alpha[r] + sum;
      m_i[r] = mnew;
    }
#pragma unroll
    for (int nt = 0; nt < 12; ++nt)
#pragma unroll
      for (int r = 0; r < 4; ++r) o[nt][r] *= alpha[r];

    // P: C/D layout -> A layout via per-wave LDS
#pragma unroll
    for (int nt = 0; nt < 4; ++nt)
#pragma unroll
      for (int r = 0; r < 4; ++r)
        P_lds[w][(quad * 4 + r) * 72 + nt * 16 + ln] = f2bf(s[nt][r]);
    __asm__ volatile("s_waitcnt lgkmcnt(0)" ::: "memory");  // wave-local write->read

    // O += P V
#pragma unroll
    for (int ks = 0; ks < 2; ++ks) {
      short8 pf = *(const short8*)&P_lds[w][ln * 72 + ks * 32 + quad * 8];
#pragma unroll
      for (int nt = 0; nt < 12; ++nt) {
        short8 vf = *(const short8*)&V_lds[(nt * 16 + ln) * 72 + ks * 32 + quad * 8];
        o[nt] = __builtin_amdgcn_mfma_f32_16x16x32_bf16(pf, vf, o[nt], 0, 0, 0);
      }
    }
  }

  // epilogue: O/l -> FP32 out [b][t][dim]  (output buffer is float32!)
#pragma unroll
  for (int r = 0; r < 4; ++r) {
    float inv = 1.0f / l_i[r];
    size_t rowoff = (size_t)(b * 512 + q0 + w * 16 + quad * 4 + r) * 192;
#pragma unroll
    for (int nt = 0; nt < 12; ++nt)
      out[rowoff + nt * 16 + ln] = o[nt][r] * inv;
  }
}

extern "C" void kernel_launch(void* const* d_in, const int* in_sizes, int n_in,
                              void* d_out, int out_size, void* d_ws, size_t ws_size,
                              hipStream_t stream) {
  // Inputs fp32 (round-2 NaN proof). OUTPUT fp32: rounds 1/3/4 decode shows
  // harness element i == my packed elements 2i/2i+1 -> 2B-vs-4B mismatch; the
  // "(bf16)" in the test label is the comparison domain (ref bf16-rounded),
  // not the storage dtype.
  const float* x = (const float*)d_in[0];
  const float* Wq = (const float*)d_in[1];
  const float* Wk = (const float*)d_in[2];
  const float* Wv = (const float*)d_in[3];
  float* out = (float*)d_out;

  char* ws = (char*)d_ws;
  const size_t QKV_BYTES = (size_t)64 * 512 * 192 * 2;  // 12,582,912
  unsigned short* q_ws = (unsigned short*)(ws);
  unsigned short* k_ws = (unsigned short*)(ws + QKV_BYTES);
  unsigned short* v_ws = (unsigned short*)(ws + 2 * QKV_BYTES);
  unsigned short* Wt = (unsigned short*)(ws + 3 * QKV_BYTES);

  hipLaunchKernelGGL(prep_w_kernel, dim3(1728), dim3(256), 0, stream, Wq, Wk, Wv, Wt);
  hipLaunchKernelGGL(proj_kernel, dim3(256, 3), dim3(256), 0, stream, x, Wt, q_ws, k_ws, v_ws);
  hipLaunchKernelGGL(attn_kernel, dim3(8, 64), dim3(256), 0, stream, q_ws, k_ws, v_ws, out);
}